// Round 21
// baseline (104.613 us; speedup 1.0000x reference)
//
#include <hip/hip_runtime.h>

#define D 16

typedef short bf16x8 __attribute__((ext_vector_type(8)));
typedef float f32x16 __attribute__((ext_vector_type(16)));
typedef float v2f __attribute__((ext_vector_type(2)));

// ---- DPP helpers (wave64), verified rounds 8-20 ----
template<int CTRL, int RMASK, bool BC>
__device__ __forceinline__ float dpp_add(float x) {
    int t = __builtin_amdgcn_update_dpp(0, __float_as_int(x), CTRL, RMASK, 0xF, BC);
    return x + __int_as_float(t);
}
__device__ __forceinline__ float wave_iscan(float x) {
    x = dpp_add<0x111, 0xF, true >(x);   // row_shr:1
    x = dpp_add<0x112, 0xF, true >(x);   // row_shr:2
    x = dpp_add<0x114, 0xF, true >(x);   // row_shr:4
    x = dpp_add<0x118, 0xF, true >(x);   // row_shr:8
    x = dpp_add<0x142, 0xA, false>(x);   // row_bcast:15
    x = dpp_add<0x143, 0xC, false>(x);   // row_bcast:31
    return x;
}

// f32 -> bf16 round-to-nearest-even
__device__ __forceinline__ short f2bf(float f) {
    unsigned u = __float_as_uint(f);
    unsigned r = u + 0x7FFFu + ((u >> 16) & 1u);
    return (short)(r >> 16);
}

// One wave per (pair,batch). 32 chunks of 16 rows, ping-pong 32KB LDS tiles:
// while chunk c is scanned (buf c&1), chunk c+1's GEMM (16 MFMA + 128
// ds_write, r13-verified H-split scheme) is spread one-slice-per-scan-row
// into the other buffer. All DS ops are volatile asm; counted lgkmcnt waits
// (in-order LDS retirement) keep the pipe full with zero drains.
__global__ __launch_bounds__(64, 1)
void sig_pde_kernel(const float* __restrict__ X, const float* __restrict__ Y,
                    float* __restrict__ out) {
    __shared__ float sinc[2 * 16 * 512];    // 64 KB: two 16-row tiles

    const int idx  = blockIdx.x;
    const int pair = idx >> 7;              // 0: XX, 1: YY, 2: XY
    const int a    = idx & 127;
    const float* Pp = (pair == 1) ? Y : X;  // row operand (dX)
    const float* Qp = (pair == 0) ? X : Y;  // col operand (dY)
    const float* prow = Pp + (size_t)a * 512 * D;
    const float* qrow = Qp + (size_t)a * 512 * D;

    const int l  = threadIdx.x;
    const int lm = l & 31;
    const int kh = l >> 5;                  // K-half of the fragment
    const int d0 = kh * 8;                  // this lane's dim offset
    const int l7 = l & 7;
    const bool lane0 = (l == 0);

    // ---- B fragments: 16 column tiles of dY, resident in registers ----
    bf16x8 Bf[16];
    #pragma unroll
    for (int n = 0; n < 16; ++n) {
        int jj = 32 * n + lm - 1;
        if (jj < 0) jj = 0;                 // col 0 garbage (masked in scan)
        const float4* y1 = (const float4*)(qrow + (size_t)(jj + 1) * D + d0);
        const float4* y0 = (const float4*)(qrow + (size_t)jj * D + d0);
        float4 h1 = y1[0], h0 = y0[0], g1 = y1[1], g0 = y0[1];
        bf16x8 f;
        f[0] = f2bf(h1.x - h0.x); f[1] = f2bf(h1.y - h0.y);
        f[2] = f2bf(h1.z - h0.z); f[3] = f2bf(h1.w - h0.w);
        f[4] = f2bf(g1.x - g0.x); f[5] = f2bf(g1.y - g0.y);
        f[6] = f2bf(g1.z - g0.z); f[7] = f2bf(g1.w - g0.w);
        Bf[n] = f;
    }

    auto loadA = [&](int b) -> bf16x8 {
        int ii = 32 * b + lm - 1;
        if (ii < 0) ii = 0;                 // row 0 garbage (never scanned)
        const float4* x1 = (const float4*)(prow + (size_t)(ii + 1) * D + d0);
        const float4* x0 = (const float4*)(prow + (size_t)ii * D + d0);
        float4 h1 = x1[0], h0 = x0[0], g1 = x1[1], g0 = x0[1];
        bf16x8 f;
        f[0] = f2bf(h1.x - h0.x); f[1] = f2bf(h1.y - h0.y);
        f[2] = f2bf(h1.z - h0.z); f[3] = f2bf(h1.w - h0.w);
        f[4] = f2bf(g1.x - g0.x); f[5] = f2bf(g1.y - g0.y);
        f[6] = f2bf(g1.z - g0.z); f[7] = f2bf(g1.w - g0.w);
        return f;
    };

    const int rot = (l >> 2) & 7;           // read-side rotation (0-conflict)

    // per-lane swizzled LDS byte addresses (reads; buf0 base)
    unsigned eaddr[8];
    #pragma unroll
    for (int m = 0; m < 8; ++m)
        eaddr[m] = (unsigned)(size_t)((const char*)sinc
                                      + (8 * l + ((m + rot) & 7)) * 4);
    // write-side swizzle offsets and per-buffer write bases (bytes)
    unsigned wsw[8];
    #pragma unroll
    for (int k = 0; k < 8; ++k) wsw[k] = (unsigned)(((l7 + k) & 7) * 4);
    unsigned wb0r = (unsigned)(size_t)((const char*)sinc
                                       + kh * 8192 + (lm & ~7) * 4);
    unsigned wb1r = wb0r + 32768;

    // ---- scan state ----
    float s[8];
    #pragma unroll
    for (int m = 0; m < 8; ++m) s[m] = 0.0f;   // K[0][j] = 1 = B + 0
    float B = 1.0f;
    v2f ghA[8], ghB[8];
    float eA[8], eB[8];                        // alpha / beta e-buffers

    const f32x16 accC = {-1.f,-1.f,-1.f,-1.f,-1.f,-1.f,-1.f,-1.f,
                         -1.f,-1.f,-1.f,-1.f,-1.f,-1.f,-1.f,-1.f};

#define WAIT8() do {                                                          \
        asm volatile("s_waitcnt lgkmcnt(8)" ::: "memory");                    \
        __builtin_amdgcn_sched_barrier(0);                                    \
    } while (0)
#define WAIT0() do {                                                          \
        asm volatile("s_waitcnt lgkmcnt(0)" ::: "memory");                    \
        __builtin_amdgcn_sched_barrier(0);                                    \
    } while (0)

#define PREFA(BUF, BOFF) do {                                                 \
        asm volatile("ds_read_b32 %0, %1 offset:%c2"                          \
                     : "=v"(BUF[0]) : "v"(eaddr[0]), "i"(BOFF));              \
        asm volatile("ds_read_b32 %0, %1 offset:%c2"                          \
                     : "=v"(BUF[1]) : "v"(eaddr[1]), "i"(BOFF));              \
        asm volatile("ds_read_b32 %0, %1 offset:%c2"                          \
                     : "=v"(BUF[2]) : "v"(eaddr[2]), "i"(BOFF));              \
        asm volatile("ds_read_b32 %0, %1 offset:%c2"                          \
                     : "=v"(BUF[3]) : "v"(eaddr[3]), "i"(BOFF));              \
        asm volatile("ds_read_b32 %0, %1 offset:%c2"                          \
                     : "=v"(BUF[4]) : "v"(eaddr[4]), "i"(BOFF));              \
        asm volatile("ds_read_b32 %0, %1 offset:%c2"                          \
                     : "=v"(BUF[5]) : "v"(eaddr[5]), "i"(BOFF));              \
        asm volatile("ds_read_b32 %0, %1 offset:%c2"                          \
                     : "=v"(BUF[6]) : "v"(eaddr[6]), "i"(BOFF));              \
        asm volatile("ds_read_b32 %0, %1 offset:%c2"                          \
                     : "=v"(BUF[7]) : "v"(eaddr[7]), "i"(BOFF));              \
    } while (0)

// store 8 values (HI half) of ACC for column-slice N into write buffer WBR
#define WSLICE(ACC, HI, N, WBR) do {                                          \
        unsigned wa_ = (WBR) + 128u * (N) + wsw[(N) & 7];                     \
        asm volatile("ds_write_b32 %0, %1"              :: "v"(wa_), "v"(ACC[8*(HI)+0])); \
        asm volatile("ds_write_b32 %0, %1 offset:2048"  :: "v"(wa_), "v"(ACC[8*(HI)+1])); \
        asm volatile("ds_write_b32 %0, %1 offset:4096"  :: "v"(wa_), "v"(ACC[8*(HI)+2])); \
        asm volatile("ds_write_b32 %0, %1 offset:6144"  :: "v"(wa_), "v"(ACC[8*(HI)+3])); \
        asm volatile("ds_write_b32 %0, %1 offset:16384" :: "v"(wa_), "v"(ACC[8*(HI)+4])); \
        asm volatile("ds_write_b32 %0, %1 offset:18432" :: "v"(wa_), "v"(ACC[8*(HI)+5])); \
        asm volatile("ds_write_b32 %0, %1 offset:20480" :: "v"(wa_), "v"(ACC[8*(HI)+6])); \
        asm volatile("ds_write_b32 %0, %1 offset:22528" :: "v"(wa_), "v"(ACC[8*(HI)+7])); \
    } while (0)

#define GHBUILD(GH, E) do {                                                   \
        float p0_ = E[0] + 1.0f;  p0_ = lane0 ? 0.0f : p0_;                   \
        float c0_ = lane0 ? 0.0f : s[0];                                      \
        GH[0][0] = p0_; GH[0][1] = c0_;                                       \
        _Pragma("unroll")                                                     \
        for (int m_ = 1; m_ < 8; ++m_) {                                      \
            v2f pc_;                                                          \
            pc_[0] = E[m_] + 1.0f;                                            \
            pc_[1] = fmaf(s[m_ - 1], E[m_], s[m_]);                          \
            GH[m_] = GH[m_ - 1] + pc_;                                        \
        }                                                                     \
    } while (0)

#define SFMA(GH) do {                                                         \
        _Pragma("unroll")                                                     \
        for (int m_ = 0; m_ < 8; ++m_)                                        \
            s[m_] = fmaf(B, GH[m_][0], GH[m_][1]);                            \
    } while (0)

// ---- row bodies ----
// row 0 (even): load alpha<-row2, consume beta(row1)/ghA; MFMA slice 0
#define ROW0G(RB, DOG) do {                                                   \
        PREFA(eA, (RB) + 2 * 2048);                                           \
        WAIT8();                                                              \
        SFMA(ghA);                                                            \
        float S_ = s[7]; float W_ = wave_iscan(S_);                           \
        GHBUILD(ghB, eB);                                                     \
        B = 1.0f + (W_ - S_);                                                 \
        if (DOG) accg = __builtin_amdgcn_mfma_f32_32x32x16_bf16(Acur, Bf[0], accC, 0, 0, 0); \
    } while (0)

// rows 1..13 (R literal): load (R odd? beta:alpha)<-row R+2, store slice R-1,
// consume the other buffer, MFMA slice R
#define ROWSTD(R, RB, WBR, HI, DOG) do {                                      \
        if ((R) & 1) { PREFA(eB, (RB) + ((R) + 2) * 2048); }                  \
        else         { PREFA(eA, (RB) + ((R) + 2) * 2048); }                  \
        WAIT8();                                                              \
        if (DOG) WSLICE(accg, HI, (R) - 1, WBR);                              \
        if ((R) & 1) {                                                        \
            SFMA(ghB);                                                        \
            float S_ = s[7]; float W_ = wave_iscan(S_);                       \
            GHBUILD(ghA, eA);                                                 \
            B = 1.0f + (W_ - S_);                                             \
        } else {                                                              \
            SFMA(ghA);                                                        \
            float S_ = s[7]; float W_ = wave_iscan(S_);                       \
            GHBUILD(ghB, eB);                                                 \
            B = 1.0f + (W_ - S_);                                             \
        }                                                                     \
        if (DOG) accg = __builtin_amdgcn_mfma_f32_32x32x16_bf16(Acur, Bf[R], accC, 0, 0, 0); \
    } while (0)

// row 14 (even): no new reads; store slice 13; MFMA slice 14
#define ROW14G(WBR, HI, DOG) do {                                             \
        if (DOG) { WAIT8(); WSLICE(accg, HI, 13, WBR); }                      \
        else     { WAIT0(); }                                                 \
        SFMA(ghA);                                                            \
        float S_ = s[7]; float W_ = wave_iscan(S_);                           \
        GHBUILD(ghB, eB);                                                     \
        B = 1.0f + (W_ - S_);                                                 \
        if (DOG) accg = __builtin_amdgcn_mfma_f32_32x32x16_bf16(Acur, Bf[14], accC, 0, 0, 0); \
    } while (0)

// row 15 (odd): store slices 14,15 (finishing next chunk's tile), then
// prefetch next chunk rows 0,1 (in-order LDS => reads see the writes)
#define ROW15G(WBR, HI, NRB) do {                                             \
        WSLICE(accg, HI, 14, WBR);                                            \
        accg = __builtin_amdgcn_mfma_f32_32x32x16_bf16(Acur, Bf[15], accC, 0, 0, 0); \
        WSLICE(accg, HI, 15, WBR);                                            \
        PREFA(eA, (NRB) + 0);                                                 \
        PREFA(eB, (NRB) + 2048);                                              \
        WAIT8();                                                              \
        SFMA(ghB);                                                            \
        float S_ = s[7]; float W_ = wave_iscan(S_);                           \
        GHBUILD(ghA, eA);                                                     \
        B = 1.0f + (W_ - S_);                                                 \
    } while (0)

// last chunk row 15: nothing outstanding, just finish grid row 511
#define ROW15L() do {                                                         \
        SFMA(ghB);                                                            \
        float S_ = s[7]; float W_ = wave_iscan(S_);                           \
        B = 1.0f + (W_ - S_);                                                 \
    } while (0)

    bf16x8 Acur = loadA(0);
    bf16x8 Anext = Acur;
    f32x16 accg;

    // ---------------- prologue: full GEMM of chunk 0 (block0 H0 -> buf0) ---
    #pragma unroll
    for (int n = 0; n < 16; ++n) {
        f32x16 t = __builtin_amdgcn_mfma_f32_32x32x16_bf16(Acur, Bf[n], accC, 0, 0, 0);
        WSLICE(t, 0, n, wb0r);
    }
    accg = __builtin_amdgcn_mfma_f32_32x32x16_bf16(Acur, Bf[0], accC, 0, 0, 0); // chunk1 s0
    PREFA(eB, 0 + 1 * 2048);   // row 1 -> beta
    PREFA(eA, 0 + 2 * 2048);   // row 2 -> alpha
    WAIT8();                   // leaves alpha; all GEMM writes + beta done
    GHBUILD(ghB, eB);

    // ---- chunk 0 scan rows 1..15 (read buf0, write buf1/H1, A0) ----
    ROWSTD( 1, 0, wb1r, 1, 1); ROWSTD( 2, 0, wb1r, 1, 1);
    ROWSTD( 3, 0, wb1r, 1, 1);
    Anext = loadA(1);
    ROWSTD( 4, 0, wb1r, 1, 1); ROWSTD( 5, 0, wb1r, 1, 1);
    ROWSTD( 6, 0, wb1r, 1, 1); ROWSTD( 7, 0, wb1r, 1, 1);
    ROWSTD( 8, 0, wb1r, 1, 1); ROWSTD( 9, 0, wb1r, 1, 1);
    ROWSTD(10, 0, wb1r, 1, 1); ROWSTD(11, 0, wb1r, 1, 1);
    ROWSTD(12, 0, wb1r, 1, 1); ROWSTD(13, 0, wb1r, 1, 1);
    ROW14G(wb1r, 1, 1);
    ROW15G(wb1r, 1, 32768);
    Acur = Anext;

    // ---------------- pairs p=0..14: chunk 2p+1 (odd), chunk 2p+2 (even) ---
    for (int p = 0; p < 15; ++p) {
        // odd chunk: read buf1, write buf0 (H0), A = A_{p+1}
        ROW0G(32768, 1);
        ROWSTD( 1, 32768, wb0r, 0, 1); ROWSTD( 2, 32768, wb0r, 0, 1);
        ROWSTD( 3, 32768, wb0r, 0, 1); ROWSTD( 4, 32768, wb0r, 0, 1);
        ROWSTD( 5, 32768, wb0r, 0, 1); ROWSTD( 6, 32768, wb0r, 0, 1);
        ROWSTD( 7, 32768, wb0r, 0, 1); ROWSTD( 8, 32768, wb0r, 0, 1);
        ROWSTD( 9, 32768, wb0r, 0, 1); ROWSTD(10, 32768, wb0r, 0, 1);
        ROWSTD(11, 32768, wb0r, 0, 1); ROWSTD(12, 32768, wb0r, 0, 1);
        ROWSTD(13, 32768, wb0r, 0, 1);
        ROW14G(wb0r, 0, 1);
        ROW15G(wb0r, 0, 0);
        // even chunk: read buf0, write buf1 (H1), A = A_{p+1}; load A_{p+2}
        ROW0G(0, 1);
        ROWSTD( 1, 0, wb1r, 1, 1); ROWSTD( 2, 0, wb1r, 1, 1);
        ROWSTD( 3, 0, wb1r, 1, 1);
        if (p < 14) Anext = loadA(p + 2);
        ROWSTD( 4, 0, wb1r, 1, 1); ROWSTD( 5, 0, wb1r, 1, 1);
        ROWSTD( 6, 0, wb1r, 1, 1); ROWSTD( 7, 0, wb1r, 1, 1);
        ROWSTD( 8, 0, wb1r, 1, 1); ROWSTD( 9, 0, wb1r, 1, 1);
        ROWSTD(10, 0, wb1r, 1, 1); ROWSTD(11, 0, wb1r, 1, 1);
        ROWSTD(12, 0, wb1r, 1, 1); ROWSTD(13, 0, wb1r, 1, 1);
        ROW14G(wb1r, 1, 1);
        ROW15G(wb1r, 1, 32768);
        if (p < 14) Acur = Anext;
    }

    // ---------------- chunk 31: read buf1, no GEMM ----------------
    ROW0G(32768, 0);
    ROWSTD( 1, 32768, wb0r, 0, 0); ROWSTD( 2, 32768, wb0r, 0, 0);
    ROWSTD( 3, 32768, wb0r, 0, 0); ROWSTD( 4, 32768, wb0r, 0, 0);
    ROWSTD( 5, 32768, wb0r, 0, 0); ROWSTD( 6, 32768, wb0r, 0, 0);
    ROWSTD( 7, 32768, wb0r, 0, 0); ROWSTD( 8, 32768, wb0r, 0, 0);
    ROWSTD( 9, 32768, wb0r, 0, 0); ROWSTD(10, 32768, wb0r, 0, 0);
    ROWSTD(11, 32768, wb0r, 0, 0); ROWSTD(12, 32768, wb0r, 0, 0);
    ROWSTD(13, 32768, wb0r, 0, 0);
    ROW14G(wb0r, 0, 0);
    ROW15L();

#undef ROW15L
#undef ROW15G
#undef ROW14G
#undef ROWSTD
#undef ROW0G
#undef SFMA
#undef GHBUILD
#undef WSLICE
#undef PREFA
#undef WAIT0
#undef WAIT8

    // K[511][511] = lane 63: B + s[7]
    if (l == 63) out[idx] = B + s[7];
}

__global__ void sig_reduce_kernel(const float* __restrict__ ws,
                                  float* __restrict__ out) {
    const int a = threadIdx.x;  // 128 threads
    float v = ws[a] + ws[128 + a] - 2.0f * ws[256 + a];
    #pragma unroll
    for (int off = 32; off >= 1; off >>= 1) v += __shfl_down(v, off, 64);
    __shared__ float partial[2];
    if ((a & 63) == 0) partial[a >> 6] = v;
    __syncthreads();
    if (a == 0) out[0] = (partial[0] + partial[1]) * (1.0f / 128.0f);
}

extern "C" void kernel_launch(void* const* d_in, const int* in_sizes, int n_in,
                              void* d_out, int out_size, void* d_ws, size_t ws_size,
                              hipStream_t stream) {
    const float* X = (const float*)d_in[0];
    const float* Y = (const float*)d_in[1];
    float* out = (float*)d_out;
    float* ws  = (float*)d_ws;   // 384 floats: [pair*128 + a]

    sig_pde_kernel<<<dim3(384), dim3(64), 0, stream>>>(X, Y, ws);
    sig_reduce_kernel<<<dim3(1), dim3(128), 0, stream>>>(ws, out);
}

// Round 22
// 92.217 us; speedup vs baseline: 1.1344x; 1.1344x over previous
//
#include <hip/hip_runtime.h>

#define D 16

typedef short bf16x8 __attribute__((ext_vector_type(8)));
typedef float f32x16 __attribute__((ext_vector_type(16)));
typedef float v2f __attribute__((ext_vector_type(2)));

// f32 -> bf16 round-to-nearest-even
__device__ __forceinline__ short f2bf(float f) {
    unsigned u = __float_as_uint(f);
    unsigned r = u + 0x7FFFu + ((u >> 16) & 1u);
    return (short)(r >> 16);
}

// ---- fused-DPP inclusive scan: 6 chained v_add_f32_dpp ----
// Each DPP op reading the VGPR written by the preceding VALU op needs 2 wait
// states (r19 failed without them); s_nop 1 provides exactly that. Without
// bound_ctrl, invalid-source lanes skip the dst write (== +0, identical to
// the builtin's zero-fill); bcast stages use the same row_masks as the
// verified 12-op scan. Half the dependent-op count of rounds 8-20.
__device__ __forceinline__ float wave_iscan(float x) {
    asm volatile(
        "s_nop 1\n\t"
        "v_add_f32_dpp %0, %0, %0 row_shr:1 row_mask:0xf bank_mask:0xf\n\t"
        "s_nop 1\n\t"
        "v_add_f32_dpp %0, %0, %0 row_shr:2 row_mask:0xf bank_mask:0xf\n\t"
        "s_nop 1\n\t"
        "v_add_f32_dpp %0, %0, %0 row_shr:4 row_mask:0xf bank_mask:0xf\n\t"
        "s_nop 1\n\t"
        "v_add_f32_dpp %0, %0, %0 row_shr:8 row_mask:0xf bank_mask:0xf\n\t"
        "s_nop 1\n\t"
        "v_add_f32_dpp %0, %0, %0 row_bcast:15 row_mask:0xa bank_mask:0xf\n\t"
        "s_nop 1\n\t"
        "v_add_f32_dpp %0, %0, %0 row_bcast:31 row_mask:0xc bank_mask:0xf\n\t"
        "s_nop 1"
        : "+v"(x));
    return x;
}

// One wave per (pair,batch); r20 structure (83.4 us, verified): counted-wait
// scan pipeline (lgkmcnt(8)) + pinned ds_read prefetch; only change vs r20
// is the fused-DPP iscan above.
__global__ __launch_bounds__(64, 1)
void sig_pde_kernel(const float* __restrict__ X, const float* __restrict__ Y,
                    float* __restrict__ out) {
    __shared__ float sinc[32 * 512];        // 64 KB (inc-1) block, swizzled

    const int idx  = blockIdx.x;
    const int pair = idx >> 7;              // 0: XX, 1: YY, 2: XY
    const int a    = idx & 127;
    const float* Pp = (pair == 1) ? Y : X;  // row operand (dX)
    const float* Qp = (pair == 0) ? X : Y;  // col operand (dY)
    const float* prow = Pp + (size_t)a * 512 * D;
    const float* qrow = Qp + (size_t)a * 512 * D;

    const int l  = threadIdx.x;
    const int lm = l & 31;
    const int kh = l >> 5;                  // K-half of the fragment
    const int d0 = kh * 8;                  // this lane's dim offset
    const bool lane0 = (l == 0);

    // ---- B fragments: 16 column tiles of dY, resident in registers ----
    bf16x8 Bf[16];
    #pragma unroll
    for (int n = 0; n < 16; ++n) {
        int jj = 32 * n + lm - 1;
        if (jj < 0) jj = 0;                 // col 0 garbage (masked in scan)
        const float4* y1 = (const float4*)(qrow + (size_t)(jj + 1) * D + d0);
        const float4* y0 = (const float4*)(qrow + (size_t)jj * D + d0);
        float4 h1 = y1[0], h0 = y0[0], g1 = y1[1], g0 = y0[1];
        bf16x8 f;
        f[0] = f2bf(h1.x - h0.x); f[1] = f2bf(h1.y - h0.y);
        f[2] = f2bf(h1.z - h0.z); f[3] = f2bf(h1.w - h0.w);
        f[4] = f2bf(g1.x - g0.x); f[5] = f2bf(g1.y - g0.y);
        f[6] = f2bf(g1.z - g0.z); f[7] = f2bf(g1.w - g0.w);
        Bf[n] = f;
    }

    auto loadA = [&](int b) -> bf16x8 {
        int ii = 32 * b + lm - 1;
        if (ii < 0) ii = 0;                 // row 0 garbage (never scanned)
        const float4* x1 = (const float4*)(prow + (size_t)(ii + 1) * D + d0);
        const float4* x0 = (const float4*)(prow + (size_t)ii * D + d0);
        float4 h1 = x1[0], h0 = x0[0], g1 = x1[1], g0 = x0[1];
        bf16x8 f;
        f[0] = f2bf(h1.x - h0.x); f[1] = f2bf(h1.y - h0.y);
        f[2] = f2bf(h1.z - h0.z); f[3] = f2bf(h1.w - h0.w);
        f[4] = f2bf(g1.x - g0.x); f[5] = f2bf(g1.y - g0.y);
        f[6] = f2bf(g1.z - g0.z); f[7] = f2bf(g1.w - g0.w);
        return f;
    };

    const int rot = (l >> 2) & 7;           // read-side rotation (0-conflict)
    float* wbase = sinc + kh * 2048;

    // persistent per-lane LDS byte addresses for the 8 swizzled e-reads
    unsigned eaddr[8];
    #pragma unroll
    for (int m = 0; m < 8; ++m)
        eaddr[m] = (unsigned)(size_t)((const char*)sinc
                                      + (8 * l + ((m + rot) & 7)) * 4);

    // ---- scan state ----
    float s[8];
    #pragma unroll
    for (int m = 0; m < 8; ++m) s[m] = 0.0f;   // K[0][j] = 1 = B + 0
    float B = 1.0f;

    v2f ghA[8], ghB[8];
    float eA[8], eB[8];

    const f32x16 accC = {-1.f,-1.f,-1.f,-1.f,-1.f,-1.f,-1.f,-1.f,
                         -1.f,-1.f,-1.f,-1.f,-1.f,-1.f,-1.f,-1.f};

// counted wait: everything except the 8 newest DS ops (the prefetch just
// issued) is complete -> previous row's buffer ready, pipe never drains.
#define WAIT8() do {                                                          \
        asm volatile("s_waitcnt lgkmcnt(8)" ::: "memory");                    \
        __builtin_amdgcn_sched_barrier(0);                                    \
    } while (0)

#define PREFA(BUF, RR) do {                                                   \
        asm volatile("ds_read_b32 %0, %1 offset:%c2"                          \
                     : "=v"(BUF[0]) : "v"(eaddr[0]), "i"((RR) * 2048));       \
        asm volatile("ds_read_b32 %0, %1 offset:%c2"                          \
                     : "=v"(BUF[1]) : "v"(eaddr[1]), "i"((RR) * 2048));       \
        asm volatile("ds_read_b32 %0, %1 offset:%c2"                          \
                     : "=v"(BUF[2]) : "v"(eaddr[2]), "i"((RR) * 2048));       \
        asm volatile("ds_read_b32 %0, %1 offset:%c2"                          \
                     : "=v"(BUF[3]) : "v"(eaddr[3]), "i"((RR) * 2048));       \
        asm volatile("ds_read_b32 %0, %1 offset:%c2"                          \
                     : "=v"(BUF[4]) : "v"(eaddr[4]), "i"((RR) * 2048));       \
        asm volatile("ds_read_b32 %0, %1 offset:%c2"                          \
                     : "=v"(BUF[5]) : "v"(eaddr[5]), "i"((RR) * 2048));       \
        asm volatile("ds_read_b32 %0, %1 offset:%c2"                          \
                     : "=v"(BUF[6]) : "v"(eaddr[6]), "i"((RR) * 2048));       \
        asm volatile("ds_read_b32 %0, %1 offset:%c2"                          \
                     : "=v"(BUF[7]) : "v"(eaddr[7]), "i"((RR) * 2048));       \
    } while (0)

#define GHBUILD(GH, E) do {                                                   \
        float p0_ = E[0] + 1.0f;  p0_ = lane0 ? 0.0f : p0_;                   \
        float c0_ = lane0 ? 0.0f : s[0];                                      \
        GH[0][0] = p0_; GH[0][1] = c0_;                                       \
        _Pragma("unroll")                                                     \
        for (int m_ = 1; m_ < 8; ++m_) {                                      \
            v2f pc_;                                                          \
            pc_[0] = E[m_] + 1.0f;                                            \
            pc_[1] = fmaf(s[m_ - 1], E[m_], s[m_]);                          \
            GH[m_] = GH[m_ - 1] + pc_;                                        \
        }                                                                     \
    } while (0)

#define SFMA(GH) do {                                                         \
        _Pragma("unroll")                                                     \
        for (int m_ = 0; m_ < 8; ++m_)                                        \
            s[m_] = fmaf(B, GH[m_][0], GH[m_][1]);                            \
    } while (0)

// row step: prefetch row RP into EFREE (top), counted wait, consume GHC,
// build GHN (row r+1) from EREADY (its reads are now complete).
#define STEP1(GHC, GHN, EFREE, EREADY, RP) do {                               \
        PREFA(EFREE, RP);                                                     \
        WAIT8();                                                              \
        SFMA(GHC);                                                            \
        float S_ = s[7];                                                      \
        float W_ = wave_iscan(S_);                                            \
        GHBUILD(GHN, EREADY);                                                 \
        B = 1.0f + (W_ - S_);                                                 \
    } while (0)

// scan tile rows FROM..31 (at block boundary the final GH build consumes a
// duplicated row-31 buffer; that GH is overwritten by the next prologue
// before any use -- provably dead).
#define SCAN_BLOCK(FROM) do {                                                 \
        PREFA(eA, (FROM));                                                    \
        PREFA(eB, (FROM) + 1);                                                \
        WAIT8();                    /* eA ready (eB is the newest 8) */       \
        GHBUILD(ghA, eA);                                                     \
        _Pragma("unroll")                                                     \
        for (int r_ = (FROM); r_ <= 31; ++r_) {                               \
            const int rp_ = (r_ + 2 <= 31) ? r_ + 2 : 31;                     \
            if (((r_ - (FROM)) & 1) == 0) STEP1(ghA, ghB, eA, eB, rp_);       \
            else                          STEP1(ghB, ghA, eB, eA, rp_);       \
        }                                                                     \
    } while (0)

    bf16x8 Acur = loadA(0);

    for (int b = 0; b < 16; ++b) {
        // ---- GEMM phase: (inc-1) rows 32b..32b+31, all 512 cols ----
        #pragma unroll
        for (int n = 0; n < 16; ++n) {
            f32x16 acc = __builtin_amdgcn_mfma_f32_32x32x16_bf16(Acur, Bf[n], accC, 0, 0, 0);
            float* p = wbase + 32 * n + (lm & ~7) + (((l & 7) + n) & 7);
            #pragma unroll
            for (int r = 0; r < 16; ++r)
                p[(r & 3) * 512 + (r >> 2) * 4096] = acc[r];
        }
        if (b < 15) Acur = loadA(b + 1);    // global prefetch under the scan

        // ---- scan phase (block 0 skips grid row 0) ----
        if (b == 0) SCAN_BLOCK(1);
        else        SCAN_BLOCK(0);
    }

#undef SCAN_BLOCK
#undef STEP1
#undef SFMA
#undef GHBUILD
#undef PREFA
#undef WAIT8

    // K[511][511] = lane 63: B + s[7]
    if (l == 63) out[idx] = B + s[7];
}

__global__ void sig_reduce_kernel(const float* __restrict__ ws,
                                  float* __restrict__ out) {
    const int a = threadIdx.x;  // 128 threads
    float v = ws[a] + ws[128 + a] - 2.0f * ws[256 + a];
    #pragma unroll
    for (int off = 32; off >= 1; off >>= 1) v += __shfl_down(v, off, 64);
    __shared__ float partial[2];
    if ((a & 63) == 0) partial[a >> 6] = v;
    __syncthreads();
    if (a == 0) out[0] = (partial[0] + partial[1]) * (1.0f / 128.0f);
}

extern "C" void kernel_launch(void* const* d_in, const int* in_sizes, int n_in,
                              void* d_out, int out_size, void* d_ws, size_t ws_size,
                              hipStream_t stream) {
    const float* X = (const float*)d_in[0];
    const float* Y = (const float*)d_in[1];
    float* out = (float*)d_out;
    float* ws  = (float*)d_ws;   // 384 floats: [pair*128 + a]

    sig_pde_kernel<<<dim3(384), dim3(64), 0, stream>>>(X, Y, ws);
    sig_reduce_kernel<<<dim3(1), dim3(128), 0, stream>>>(ws, out);
}